// Round 15
// baseline (345.345 us; speedup 1.0000x reference)
//
#include <hip/hip_runtime.h>
#include <hip/hip_bf16.h>
#include <cstdint>
#include <cstddef>

typedef __attribute__((ext_vector_type(8))) short bf16x8;
typedef __attribute__((ext_vector_type(8))) unsigned short u16x8;
typedef __attribute__((ext_vector_type(4))) float f32x4;
typedef unsigned short u16;

__device__ __forceinline__ u16 f2bf(float f) {
    unsigned int u = __float_as_uint(f);
    u += 0x7fffu + ((u >> 16) & 1u);   // RNE
    return (u16)(u >> 16);
}
__device__ __forceinline__ float bf2f(u16 u) {
    return __uint_as_float(((unsigned int)u) << 16);
}

__device__ __forceinline__ void gload16(const void* g, void* l) {
    __builtin_amdgcn_global_load_lds((const __attribute__((address_space(1))) void*)g,
                                     (__attribute__((address_space(3))) void*)l,
                                     16, 0, 0);
}

// ---- fused prologue: {W1,W2,W3 f32->bf16 into contiguous slab} + {At1 = g⊙X} -
__global__ void prologue(const float* __restrict__ W1,
                         const float* __restrict__ W2,
                         const float* __restrict__ W3,
                         u16* __restrict__ Wb,
                         const float* __restrict__ X,
                         const float* __restrict__ gate,
                         u16* __restrict__ At1) {
    const int bid = blockIdx.x;
    if (bid < 8192) {
        const int idx = bid * 256 + threadIdx.x;
        const float* src;
        size_t off;
        if (idx < 524288)       { src = W1; off = (size_t)idx * 8; }
        else if (idx < 1572864) { src = W2; off = (size_t)(idx - 524288) * 8; }
        else                    { src = W3; off = (size_t)(idx - 1572864) * 8; }
        float4 v0 = ((const float4*)(src + off))[0];
        float4 v1 = ((const float4*)(src + off))[1];
        u16x8 r;
        r[0] = f2bf(v0.x); r[1] = f2bf(v0.y); r[2] = f2bf(v0.z); r[3] = f2bf(v0.w);
        r[4] = f2bf(v1.x); r[5] = f2bf(v1.y); r[6] = f2bf(v1.z); r[7] = f2bf(v1.w);
        *(u16x8*)(Wb + (size_t)idx * 8) = r;
    } else {
        const size_t idx = ((size_t)(bid - 8192) * 256 + threadIdx.x) * 8;  // [8192][8][512]
        const size_t b = idx >> 12;
        const int rem = (int)(idx & 4095);
        const int e = rem >> 9;
        const int k = rem & 511;
        const float g = gate[b * 8 + e];
        const float* src = X + b * 512 + k;
        float4 v0 = ((const float4*)src)[0];
        float4 v1 = ((const float4*)src)[1];
        u16x8 r;
        r[0] = f2bf(g * v0.x); r[1] = f2bf(g * v0.y); r[2] = f2bf(g * v0.z); r[3] = f2bf(g * v0.w);
        r[4] = f2bf(g * v1.x); r[5] = f2bf(g * v1.y); r[6] = f2bf(g * v1.z); r[7] = f2bf(g * v1.w);
        *(u16x8*)(At1 + idx) = r;
    }
}

// ---------------- L1 fused GEMM: 128xBN, S=1, epilogue -> At2 -----------------
// BN=64 -> grid 1024 = 4 blocks/CU (V5's verified occupancy regime).
// Epilogue LDS layout kept identical to the replay-validated version:
// WsL=(float*)As, BiasL=(float*)Bs.
template<int BN>
__global__ __launch_bounds__(256, 4)
void moe_gemm_l1f(const u16* __restrict__ At,
                  const u16* __restrict__ Bw,
                  const float* __restrict__ gate,
                  const float* __restrict__ bias,
                  u16* __restrict__ At2out,
                  int N, int K, int Ktot, int log2nk, int kts, int bxbits) {
    constexpr int BM = 128, BK = 64, NE = 8;
    constexpr int NI = BN / 32;        // C frags per wave in n
    constexpr int NB_IT = BN / 32;     // B staging iters
    __shared__ u16 As[BM * BK];        // 16 KB
    __shared__ u16 Bs[BN * BK];        // 8 KB (BN=64)

    const int tid  = threadIdx.x;
    const int lane = tid & 63;
    const int wave = tid >> 6;
    const int wr = wave >> 1, wc = wave & 1;
    const int fr = lane & 15;
    const int fg = lane >> 4;

    const int bid = blockIdx.x;
    const int xcd = bid & 7, idx = bid >> 3;
    const int bx  = idx & ((1 << bxbits) - 1);
    const int by  = xcd * 8 + (idx >> bxbits);
    const int m0  = by * BM;
    const int n0  = bx * BN;

    int rowoffA[4], ldsA[4], rowoffB[NB_IT], ldsB[NB_IT];
    #pragma unroll
    for (int it = 0; it < 4; ++it) {
        const int c   = it * 4 + wave;
        const int L   = c * 1024 + lane * 16;
        const int row = L >> 7;
        const int cb  = (L & 127) ^ ((row & 7) << 4);
        rowoffA[it] = row * (Ktot * 2) + cb;
        ldsA[it]    = c * 1024;
    }
    #pragma unroll
    for (int it = 0; it < NB_IT; ++it) {
        const int c   = it * 4 + wave;
        const int L   = c * 1024 + lane * 16;
        const int row = L >> 7;
        const int cb  = (L & 127) ^ ((row & 7) << 4);
        rowoffB[it] = row * (K * 2) + cb;
        ldsB[it]    = c * 1024;
    }

    const char* Abase = (const char*)(At + (size_t)m0 * Ktot);
    const char* Bbase = (const char*)(Bw + (size_t)n0 * K);
    const size_t Bestride = (size_t)N * K * 2;
    const int swz    = (fr & 7) << 4;
    const int nkmask = (1 << log2nk) - 1;

    f32x4 acc[4][NI];
    #pragma unroll
    for (int a = 0; a < 4; ++a)
        #pragma unroll
        for (int b = 0; b < NI; ++b) acc[a][b] = f32x4{0.f, 0.f, 0.f, 0.f};

    for (int kt = 0; kt < kts; ++kt) {
        __syncthreads();
        const char* Ab = Abase + kt * 128;
        const char* Bb = Bbase + (size_t)(kt >> log2nk) * Bestride + (kt & nkmask) * 128;
        #pragma unroll
        for (int it = 0; it < 4; ++it)
            gload16(Ab + rowoffA[it], (char*)As + ldsA[it]);
        #pragma unroll
        for (int it = 0; it < NB_IT; ++it)
            gload16(Bb + rowoffB[it], (char*)Bs + ldsB[it]);
        __syncthreads();

        #pragma unroll
        for (int kk = 0; kk < 2; ++kk) {
            const int kb = kk * 64 + fg * 16;
            bf16x8 af[4], bfr[NI];
            #pragma unroll
            for (int mi = 0; mi < 4; ++mi) {
                const int r = wr * 64 + mi * 16 + fr;
                af[mi] = *(const bf16x8*)((const char*)As + r * 128 + (kb ^ swz));
            }
            #pragma unroll
            for (int ni = 0; ni < NI; ++ni) {
                const int cc = wc * (BN / 2) + ni * 16 + fr;
                bfr[ni] = *(const bf16x8*)((const char*)Bs + cc * 128 + (kb ^ swz));
            }
            #pragma unroll
            for (int mi = 0; mi < 4; ++mi)
                #pragma unroll
                for (int ni = 0; ni < NI; ++ni)
                    acc[mi][ni] = __builtin_amdgcn_mfma_f32_16x16x32_bf16(
                        af[mi], bfr[ni], acc[mi][ni], 0, 0, 0);
        }
    }

    // fused epilogue: bias + ELU + 8 gated expert copies -> At2out
    __syncthreads();
    float* WsL   = (float*)As;       // [128][8] gates (4 KB of As)
    float* BiasL = (float*)Bs;       // [8][BN] bias (2 KB of Bs)
    {
        const int j = tid * 4;
        *(float4*)&WsL[j] = *(const float4*)&gate[(size_t)(m0 + (j >> 3)) * 8 + (j & 7)];
        if (j < NE * BN)
            *(float4*)&BiasL[j] = *(const float4*)&bias[(size_t)(j / BN) * N + n0 + (j & (BN - 1))];
    }
    __syncthreads();

    float bias8[NI][8];
    #pragma unroll
    for (int ni = 0; ni < NI; ++ni)
        #pragma unroll
        for (int e = 0; e < 8; ++e)
            bias8[ni][e] = BiasL[e * BN + wc * (BN / 2) + ni * 16 + fr];

    #pragma unroll
    for (int mi = 0; mi < 4; ++mi) {
        #pragma unroll
        for (int j = 0; j < 4; ++j) {
            const int r = wr * 64 + mi * 16 + fg * 4 + j;
            float g8[8];
            #pragma unroll
            for (int e = 0; e < 8; ++e) g8[e] = WsL[r * 8 + e];
            #pragma unroll
            for (int ni = 0; ni < NI; ++ni) {
                float v = acc[mi][ni][j];
                #pragma unroll
                for (int e = 0; e < 8; ++e) v += g8[e] * bias8[ni][e];
                v = v > 0.f ? v : expm1f(v);
                const int cl = wc * (BN / 2) + ni * 16 + fr;
                const size_t base = (size_t)(m0 + r) * 8192 + n0 + cl;
                #pragma unroll
                for (int e = 0; e < 8; ++e)
                    At2out[base + e * 1024] = f2bf(g8[e] * v);
            }
        }
    }
}

// ---------------- 256x256 split-K GEMM, 2-barrier free-run frame (V7) ---------
template<bool BF16P>
__global__ __launch_bounds__(512, 2)
void moe_gemm_2b(const u16* __restrict__ At, const u16* __restrict__ Bw,
                 void* __restrict__ P,
                 int N, int K, int Ktot, int log2nk, int kts, int bxbits) {
    __shared__ char lds[2][65536];

    const int tid  = threadIdx.x;
    const int lane = tid & 63;
    const int wave = tid >> 6;
    const int wm   = wave >> 2;
    const int wn   = wave & 3;
    const int fr   = lane & 15;
    const int fg   = lane >> 4;
    const int swz  = (fr & 7) << 4;

    const int bid  = blockIdx.x;
    const int wgid = (bid & 7) * 32 + (bid >> 3);
    const int bx   = wgid & ((1 << bxbits) - 1);
    const int by   = (wgid >> bxbits) & 31;
    const int s    = wgid >> (bxbits + 5);
    const int m0   = by * 256;
    const int n0   = bx * 256;

    int rowA[2], rowB[2], ldso[2];
    #pragma unroll
    for (int it = 0; it < 2; ++it) {
        const int o  = (it * 8 + wave) * 1024 + lane * 16;
        const int r  = o >> 7;
        const int cb = (o & 127) ^ ((r & 7) << 4);
        rowA[it] = r * (Ktot * 2) + cb;
        rowB[it] = r * (K * 2) + cb;
        ldso[it] = o;
    }

    const char* Ab0 = (const char*)(At + (size_t)m0 * Ktot);
    const char* Ab1 = Ab0 + (size_t)128 * Ktot * 2;
    const char* Bb0 = (const char*)(Bw + (size_t)n0 * K);
    const char* Bb1 = Bb0 + (size_t)128 * K * 2;
    const size_t Best = (size_t)N * K * 2;
    const int nkm = (1 << log2nk) - 1;
    const int kt0 = s * kts;

#define STAGE_A(BUF, KTG) do { \
    const char* _a0 = Ab0 + (size_t)(KTG) * 128; \
    const char* _a1 = Ab1 + (size_t)(KTG) * 128; \
    char* _l = lds[BUF]; \
    gload16(_a0 + rowA[0], _l + ldso[0]); \
    gload16(_a0 + rowA[1], _l + ldso[1]); \
    gload16(_a1 + rowA[0], _l + 16384 + ldso[0]); \
    gload16(_a1 + rowA[1], _l + 16384 + ldso[1]); \
} while (0)

#define STAGE_B(BUF, KTG) do { \
    const int _kg = (KTG); \
    const size_t _bo = (size_t)(_kg >> log2nk) * Best + (size_t)(_kg & nkm) * 128; \
    char* _l = lds[BUF] + 32768; \
    gload16(Bb0 + _bo + rowB[0], _l + ldso[0]); \
    gload16(Bb0 + _bo + rowB[1], _l + ldso[1]); \
    gload16(Bb1 + _bo + rowB[0], _l + 16384 + ldso[0]); \
    gload16(Bb1 + _bo + rowB[1], _l + 16384 + ldso[1]); \
} while (0)

    f32x4 acc[8][4];
    #pragma unroll
    for (int i = 0; i < 8; ++i)
        #pragma unroll
        for (int j = 0; j < 4; ++j) acc[i][j] = f32x4{0.f, 0.f, 0.f, 0.f};

    bf16x8 af[2][4], bfA[2][2], bfB[2][2];

    STAGE_A(0, kt0);
    STAGE_B(0, kt0);
    STAGE_A(1, kt0 + 1);
    __builtin_amdgcn_sched_barrier(0);
    asm volatile("s_waitcnt vmcnt(4)" ::: "memory");
    __builtin_amdgcn_s_barrier();
    __builtin_amdgcn_sched_barrier(0);

    for (int t = 0; t < kts; ++t) {
        const int BUF = t & 1;
        const char* _abase = lds[BUF] + wm * 16384 + fr * 128;
        const char* _bbase = lds[BUF] + 32768 + (wn >> 1) * 16384 + ((wn & 1) * 64 + fr) * 128;
        const int k0 = (fg * 16) ^ swz;
        const int k1 = (64 + fg * 16) ^ swz;

        if (t + 1 < kts) STAGE_B(BUF ^ 1, kt0 + t + 1);

        #pragma unroll
        for (int i = 0; i < 4; ++i) {
            af[0][i] = *(const bf16x8*)(_abase + i * 2048 + k0);
            af[1][i] = *(const bf16x8*)(_abase + i * 2048 + k1);
        }
        #pragma unroll
        for (int j = 0; j < 2; ++j) {
            bfA[0][j] = *(const bf16x8*)(_bbase + j * 2048 + k0);
            bfA[1][j] = *(const bf16x8*)(_bbase + j * 2048 + k1);
        }
        __builtin_amdgcn_s_setprio(1);
        #pragma unroll
        for (int i = 0; i < 4; ++i)
            #pragma unroll
            for (int j = 0; j < 2; ++j) {
                acc[i][j] = __builtin_amdgcn_mfma_f32_16x16x32_bf16(af[0][i], bfA[0][j], acc[i][j], 0, 0, 0);
                acc[i][j] = __builtin_amdgcn_mfma_f32_16x16x32_bf16(af[1][i], bfA[1][j], acc[i][j], 0, 0, 0);
            }
        __builtin_amdgcn_s_setprio(0);

        #pragma unroll
        for (int j = 0; j < 2; ++j) {
            bfB[0][j] = *(const bf16x8*)(_bbase + (2 + j) * 2048 + k0);
            bfB[1][j] = *(const bf16x8*)(_bbase + (2 + j) * 2048 + k1);
        }
        __builtin_amdgcn_s_setprio(1);
        #pragma unroll
        for (int i = 0; i < 4; ++i)
            #pragma unroll
            for (int j = 0; j < 2; ++j) {
                acc[i][2 + j] = __builtin_amdgcn_mfma_f32_16x16x32_bf16(af[0][i], bfB[0][j], acc[i][2 + j], 0, 0, 0);
                acc[i][2 + j] = __builtin_amdgcn_mfma_f32_16x16x32_bf16(af[1][i], bfB[1][j], acc[i][2 + j], 0, 0, 0);
            }
        __builtin_amdgcn_s_setprio(0);

        #pragma unroll
        for (int i = 0; i < 4; ++i) {
            af[0][i] = *(const bf16x8*)(_abase + (4 + i) * 2048 + k0);
            af[1][i] = *(const bf16x8*)(_abase + (4 + i) * 2048 + k1);
        }
        __builtin_amdgcn_s_setprio(1);
        #pragma unroll
        for (int i = 0; i < 4; ++i)
            #pragma unroll
            for (int j = 0; j < 2; ++j) {
                acc[4 + i][2 + j] = __builtin_amdgcn_mfma_f32_16x16x32_bf16(af[0][i], bfB[0][j], acc[4 + i][2 + j], 0, 0, 0);
                acc[4 + i][2 + j] = __builtin_amdgcn_mfma_f32_16x16x32_bf16(af[1][i], bfB[1][j], acc[4 + i][2 + j], 0, 0, 0);
            }
        __builtin_amdgcn_s_setprio(0);

        __builtin_amdgcn_sched_barrier(0);
        __builtin_amdgcn_s_barrier();
        __builtin_amdgcn_sched_barrier(0);

        if (t + 2 < kts) STAGE_A(BUF, kt0 + t + 2);

        __builtin_amdgcn_s_setprio(1);
        #pragma unroll
        for (int i = 0; i < 4; ++i)
            #pragma unroll
            for (int j = 0; j < 2; ++j) {
                acc[4 + i][j] = __builtin_amdgcn_mfma_f32_16x16x32_bf16(af[0][i], bfA[0][j], acc[4 + i][j], 0, 0, 0);
                acc[4 + i][j] = __builtin_amdgcn_mfma_f32_16x16x32_bf16(af[1][i], bfA[1][j], acc[4 + i][j], 0, 0, 0);
            }
        __builtin_amdgcn_s_setprio(0);

        __builtin_amdgcn_sched_barrier(0);
        if (t + 2 < kts) {
            asm volatile("s_waitcnt vmcnt(4)" ::: "memory");
        } else {
            asm volatile("s_waitcnt vmcnt(0)" ::: "memory");
        }
        __builtin_amdgcn_s_barrier();
        __builtin_amdgcn_sched_barrier(0);
    }

    const size_t pbase = ((size_t)s * 8192 + m0 + wm * 128) * N + (n0 + wn * 64);
    #pragma unroll
    for (int mi = 0; mi < 8; ++mi)
        #pragma unroll
        for (int j = 0; j < 4; ++j) {
            const int r = mi * 16 + fg * 4 + j;
            #pragma unroll
            for (int ni = 0; ni < 4; ++ni) {
                const size_t off = pbase + (size_t)r * N + ni * 16 + fr;
                if (BF16P) ((u16*)P)[off]   = f2bf(acc[mi][ni][j]);
                else       ((float*)P)[off] = acc[mi][ni][j];
            }
        }
#undef STAGE_A
#undef STAGE_B
}

// ---------------- split-K reduce (bf16 partials): + gate-bias -----------------
template<int S>
__global__ void moe_reduce_bf16(const u16* __restrict__ P,
                                const float* __restrict__ gate,
                                const float* __restrict__ bias,
                                float* __restrict__ outp,
                                int log2N) {
    const int i = blockIdx.x * 256 + threadIdx.x;
    const size_t el = (size_t)i * 8;
    const size_t b = el >> log2N;
    const int n = (int)(el & ((1 << log2N) - 1));
    const size_t MN = (size_t)8192 << log2N;
    float v[8];
    u16x8 p0 = *(const u16x8*)(P + el);
    #pragma unroll
    for (int j = 0; j < 8; ++j) v[j] = bf2f(p0[j]);
    #pragma unroll
    for (int s = 1; s < S; ++s) {
        u16x8 ps = *(const u16x8*)(P + (size_t)s * MN + el);
        #pragma unroll
        for (int j = 0; j < 8; ++j) v[j] += bf2f(ps[j]);
    }
    #pragma unroll
    for (int e = 0; e < 8; ++e) {
        const float g = gate[b * 8 + e];
        const float* bb = bias + ((size_t)e << log2N) + n;
        float4 b0 = ((const float4*)bb)[0], b1 = ((const float4*)bb)[1];
        v[0] += g * b0.x; v[1] += g * b0.y; v[2] += g * b0.z; v[3] += g * b0.w;
        v[4] += g * b1.x; v[5] += g * b1.y; v[6] += g * b1.z; v[7] += g * b1.w;
    }
    float4 o0 = {v[0], v[1], v[2], v[3]};
    float4 o1 = {v[4], v[5], v[6], v[7]};
    ((float4*)(outp + el))[0] = o0;
    ((float4*)(outp + el))[1] = o1;
}

// ---- fused: reduce(S=2 bf16, bias b2, ELU) + atilde (8 gated expert copies) --
__global__ void reduce_atilde2(const u16* __restrict__ P,
                               const float* __restrict__ gate,
                               const float* __restrict__ bias,
                               u16* __restrict__ At) {
    const int idx = blockIdx.x * 256 + threadIdx.x;   // 8192*128 total
    const int h = (idx & 127) * 8;
    const size_t b = idx >> 7;
    const size_t MH = (size_t)8192 * 1024;
    const u16* p = P + b * 1024 + h;
    u16x8 a0 = *(const u16x8*)p;
    u16x8 a1 = *(const u16x8*)(p + MH);
    float m[8];
    #pragma unroll
    for (int j = 0; j < 8; ++j) m[j] = bf2f(a0[j]) + bf2f(a1[j]);
    float4 g0 = *(const float4*)&gate[b * 8];
    float4 g1 = *(const float4*)&gate[b * 8 + 4];
    float gg[8] = {g0.x, g0.y, g0.z, g0.w, g1.x, g1.y, g1.z, g1.w};
    #pragma unroll
    for (int e = 0; e < 8; ++e) {
        const float* bb = bias + e * 1024 + h;
        float4 b0 = ((const float4*)bb)[0], b1 = ((const float4*)bb)[1];
        m[0] += gg[e] * b0.x; m[1] += gg[e] * b0.y; m[2] += gg[e] * b0.z; m[3] += gg[e] * b0.w;
        m[4] += gg[e] * b1.x; m[5] += gg[e] * b1.y; m[6] += gg[e] * b1.z; m[7] += gg[e] * b1.w;
    }
    #pragma unroll
    for (int j = 0; j < 8; ++j) m[j] = m[j] > 0.f ? m[j] : expm1f(m[j]);
    u16* o = At + b * 8192 + h;
    #pragma unroll
    for (int e = 0; e < 8; ++e) {
        u16x8 r;
        #pragma unroll
        for (int j = 0; j < 8; ++j) r[j] = f2bf(gg[e] * m[j]);
        *(u16x8*)(o + e * 1024) = r;
    }
}

// ---------------- launcher ----------------------------------------------------
extern "C" void kernel_launch(void* const* d_in, const int* in_sizes, int n_in,
                              void* d_out, int out_size, void* d_ws, size_t ws_size,
                              hipStream_t stream) {
    const float* X  = (const float*)d_in[0];   // [8192,512]
    const float* W  = (const float*)d_in[1];   // [8192,8]
    const float* W1 = (const float*)d_in[2];   // [8,1024,512]
    const float* b1 = (const float*)d_in[3];   // [8,1024]
    const float* W2 = (const float*)d_in[4];   // [8,1024,1024]
    const float* b2 = (const float*)d_in[5];   // [8,1024]
    const float* W3 = (const float*)d_in[6];   // [8,512,1024]
    const float* b3 = (const float*)d_in[7];   // [8,512]
    float* out = (float*)d_out;

    char* ws = (char*)d_ws;
    u16* W1b  = (u16*)ws;  ws += (size_t)8 * 1024 * 512 * 2;     //  8.4 MB
    u16* W2b  = (u16*)ws;  ws += (size_t)8 * 1024 * 1024 * 2;    // 16.8 MB
    u16* W3b  = (u16*)ws;  ws += (size_t)8 * 512 * 1024 * 2;     //  8.4 MB
    u16* At1  = (u16*)ws;  ws += (size_t)8192 * 4096 * 2;        //   67 MB
    u16* At2  = (u16*)ws;  ws += (size_t)8192 * 8192 * 2;        //  134 MB

    // bf16 partial slabs reuse dead regions of At1 (67 MB):
    u16* P2 = At1;   // S=2 x [8192][1024] bf16 = 33.5 MB  (At1 dead after L1)
    u16* P3 = At1;   // S=4 x [8192][512]  bf16 = 33.5 MB  (P2 consumed)

    dim3 blk(256);

    // fused prologue: weight converts + At1 = gate ⊙ X (one dispatch)
    prologue<<<24576, blk, 0, stream>>>(W1, W2, W3, W1b, X, W, At1);

    // L1: fused S=1 GEMM over At1 (BN=64, grid 1024 = 4 blocks/CU) -> At2
    moe_gemm_l1f<64><<<1024, blk, 0, stream>>>(At1, W1b, W, b1, At2, 1024, 512, 4096, 3, 64, 4);

    // L2: S=2 GEMM over At2 (bf16 partials); fused reduce+atilde -> At3(=At2)
    moe_gemm_2b<true><<<256, 512, 0, stream>>>(At2, W2b, (void*)P2, 1024, 1024, 8192, 4, 64, 2);
    reduce_atilde2<<<4096, blk, 0, stream>>>(P2, W, b2, At2);

    // L3: S=4 GEMM over At2 (bf16 partials); reduce -> out (f32)
    moe_gemm_2b<true><<<256, 512, 0, stream>>>(At2, W3b, (void*)P3, 512, 1024, 8192, 4, 32, 1);
    moe_reduce_bf16<4><<<2048, blk, 0, stream>>>(P3, W, b3, out, 9);
}

// Round 16
// 331.603 us; speedup vs baseline: 1.0414x; 1.0414x over previous
//
#include <hip/hip_runtime.h>
#include <hip/hip_bf16.h>
#include <cstdint>
#include <cstddef>

typedef __attribute__((ext_vector_type(8))) short bf16x8;
typedef __attribute__((ext_vector_type(8))) unsigned short u16x8;
typedef __attribute__((ext_vector_type(4))) float f32x4;
typedef unsigned short u16;

__device__ __forceinline__ u16 f2bf(float f) {
    unsigned int u = __float_as_uint(f);
    u += 0x7fffu + ((u >> 16) & 1u);   // RNE
    return (u16)(u >> 16);
}
__device__ __forceinline__ float bf2f(u16 u) {
    return __uint_as_float(((unsigned int)u) << 16);
}

__device__ __forceinline__ void gload16(const void* g, void* l) {
    __builtin_amdgcn_global_load_lds((const __attribute__((address_space(1))) void*)g,
                                     (__attribute__((address_space(3))) void*)l,
                                     16, 0, 0);
}

// ---- fused prologue: {W1,W2,W3 f32->bf16 into contiguous slab} + {At1 = g⊙X} -
// blocks 0..8191: weight convert (2097152 threads x 8 elems).
// blocks 8192..24575: atilde1 (4194304 threads x 8 elems over [8192,8,512]).
// Pure elementwise, disjoint writes, no LDS/barriers -> replay-safe by design.
__global__ void prologue(const float* __restrict__ W1,
                         const float* __restrict__ W2,
                         const float* __restrict__ W3,
                         u16* __restrict__ Wb,
                         const float* __restrict__ X,
                         const float* __restrict__ gate,
                         u16* __restrict__ At1) {
    const int bid = blockIdx.x;
    if (bid < 8192) {
        const int idx = bid * 256 + threadIdx.x;
        const float* src;
        size_t off;
        if (idx < 524288)       { src = W1; off = (size_t)idx * 8; }
        else if (idx < 1572864) { src = W2; off = (size_t)(idx - 524288) * 8; }
        else                    { src = W3; off = (size_t)(idx - 1572864) * 8; }
        float4 v0 = ((const float4*)(src + off))[0];
        float4 v1 = ((const float4*)(src + off))[1];
        u16x8 r;
        r[0] = f2bf(v0.x); r[1] = f2bf(v0.y); r[2] = f2bf(v0.z); r[3] = f2bf(v0.w);
        r[4] = f2bf(v1.x); r[5] = f2bf(v1.y); r[6] = f2bf(v1.z); r[7] = f2bf(v1.w);
        *(u16x8*)(Wb + (size_t)idx * 8) = r;
    } else {
        const size_t idx = ((size_t)(bid - 8192) * 256 + threadIdx.x) * 8;  // [8192][8][512]
        const size_t b = idx >> 12;              // log2(8*512)=12
        const int rem = (int)(idx & 4095);
        const int e = rem >> 9;                  // log2(512)=9
        const int k = rem & 511;
        const float g = gate[b * 8 + e];
        const float* src = X + b * 512 + k;
        float4 v0 = ((const float4*)src)[0];
        float4 v1 = ((const float4*)src)[1];
        u16x8 r;
        r[0] = f2bf(g * v0.x); r[1] = f2bf(g * v0.y); r[2] = f2bf(g * v0.z); r[3] = f2bf(g * v0.w);
        r[4] = f2bf(g * v1.x); r[5] = f2bf(g * v1.y); r[6] = f2bf(g * v1.z); r[7] = f2bf(g * v1.w);
        *(u16x8*)(At1 + idx) = r;
    }
}

// ---------------- L1 fused GEMM: 128x128, S=1, epilogue -> At2 ----------------
// (verbatim round-11/13/14 version: replay-validated in rounds 9/10/11/13/14)
__global__ __launch_bounds__(256, 4)
void moe_gemm_l1f(const u16* __restrict__ At,
                  const u16* __restrict__ Bw,
                  const float* __restrict__ gate,
                  const float* __restrict__ bias,
                  u16* __restrict__ At2out,
                  int N, int K, int Ktot, int log2nk, int kts) {
    constexpr int BM = 128, BN = 128, BK = 64;
    __shared__ u16 As[BM * BK];
    __shared__ u16 Bs[BN * BK];

    const int tid  = threadIdx.x;
    const int lane = tid & 63;
    const int wave = tid >> 6;
    const int wr = wave >> 1, wc = wave & 1;
    const int fr = lane & 15;
    const int fg = lane >> 4;

    const int bid = blockIdx.x;
    const int xcd = bid & 7, idx = bid >> 3;
    const int bx  = idx & 7;
    const int by  = xcd * 8 + (idx >> 3);
    const int m0  = by * BM;
    const int n0  = bx * BN;

    int rowoffA[4], rowoffB[4], ldsoff[4];
    #pragma unroll
    for (int it = 0; it < 4; ++it) {
        const int c   = it * 4 + wave;
        const int L   = c * 1024 + lane * 16;
        const int row = L >> 7;
        const int cb  = (L & 127) ^ ((row & 7) << 4);
        rowoffA[it] = row * (Ktot * 2) + cb;
        rowoffB[it] = row * (K * 2) + cb;
        ldsoff[it]  = c * 1024;
    }

    const char* Abase = (const char*)(At + (size_t)m0 * Ktot);
    const char* Bbase = (const char*)(Bw + (size_t)n0 * K);
    const size_t Bestride = (size_t)N * K * 2;
    const int swz    = (fr & 7) << 4;
    const int nkmask = (1 << log2nk) - 1;

    f32x4 acc[4][4];
    #pragma unroll
    for (int a = 0; a < 4; ++a)
        #pragma unroll
        for (int b = 0; b < 4; ++b) acc[a][b] = f32x4{0.f, 0.f, 0.f, 0.f};

    for (int kt = 0; kt < kts; ++kt) {
        __syncthreads();
        const char* Ab = Abase + kt * 128;
        const char* Bb = Bbase + (size_t)(kt >> log2nk) * Bestride + (kt & nkmask) * 128;
        #pragma unroll
        for (int it = 0; it < 4; ++it) {
            gload16(Ab + rowoffA[it], (char*)As + ldsoff[it]);
            gload16(Bb + rowoffB[it], (char*)Bs + ldsoff[it]);
        }
        __syncthreads();

        #pragma unroll
        for (int kk = 0; kk < 2; ++kk) {
            const int kb = kk * 64 + fg * 16;
            bf16x8 af[4], bfr[4];
            #pragma unroll
            for (int mi = 0; mi < 4; ++mi) {
                const int r  = wr * 64 + mi * 16 + fr;
                af[mi]  = *(const bf16x8*)((const char*)As + r * 128 + (kb ^ swz));
                const int cc = wc * 64 + mi * 16 + fr;
                bfr[mi] = *(const bf16x8*)((const char*)Bs + cc * 128 + (kb ^ swz));
            }
            #pragma unroll
            for (int mi = 0; mi < 4; ++mi)
                #pragma unroll
                for (int ni = 0; ni < 4; ++ni)
                    acc[mi][ni] = __builtin_amdgcn_mfma_f32_16x16x32_bf16(
                        af[mi], bfr[ni], acc[mi][ni], 0, 0, 0);
        }
    }

    // fused epilogue: bias + ELU + 8 gated expert copies -> At2out
    __syncthreads();
    float* WsL   = (float*)As;
    float* BiasL = (float*)Bs;
    {
        const int j = tid * 4;
        *(float4*)&WsL[j]   = *(const float4*)&gate[(size_t)(m0 + (j >> 3)) * 8 + (j & 7)];
        *(float4*)&BiasL[j] = *(const float4*)&bias[(size_t)(j >> 7) * N + n0 + (j & 127)];
    }
    __syncthreads();

    float bias8[4][8];
    #pragma unroll
    for (int ni = 0; ni < 4; ++ni)
        #pragma unroll
        for (int e = 0; e < 8; ++e)
            bias8[ni][e] = BiasL[e * BN + wc * 64 + ni * 16 + fr];

    #pragma unroll
    for (int mi = 0; mi < 4; ++mi) {
        #pragma unroll
        for (int j = 0; j < 4; ++j) {
            const int r = wr * 64 + mi * 16 + fg * 4 + j;
            float g8[8];
            #pragma unroll
            for (int e = 0; e < 8; ++e) g8[e] = WsL[r * 8 + e];
            #pragma unroll
            for (int ni = 0; ni < 4; ++ni) {
                float v = acc[mi][ni][j];
                #pragma unroll
                for (int e = 0; e < 8; ++e) v += g8[e] * bias8[ni][e];
                v = v > 0.f ? v : expm1f(v);
                const int cl = wc * 64 + ni * 16 + fr;
                const size_t base = (size_t)(m0 + r) * 8192 + n0 + cl;
                #pragma unroll
                for (int e = 0; e < 8; ++e)
                    At2out[base + e * 1024] = f2bf(g8[e] * v);
            }
        }
    }
}

// ---------------- 256x256 split-K GEMM, 2-barrier free-run frame (V7) ---------
template<bool BF16P>
__global__ __launch_bounds__(512, 2)
void moe_gemm_2b(const u16* __restrict__ At, const u16* __restrict__ Bw,
                 void* __restrict__ P,
                 int N, int K, int Ktot, int log2nk, int kts, int bxbits) {
    __shared__ char lds[2][65536];

    const int tid  = threadIdx.x;
    const int lane = tid & 63;
    const int wave = tid >> 6;
    const int wm   = wave >> 2;
    const int wn   = wave & 3;
    const int fr   = lane & 15;
    const int fg   = lane >> 4;
    const int swz  = (fr & 7) << 4;

    const int bid  = blockIdx.x;
    const int wgid = (bid & 7) * 32 + (bid >> 3);
    const int bx   = wgid & ((1 << bxbits) - 1);
    const int by   = (wgid >> bxbits) & 31;
    const int s    = wgid >> (bxbits + 5);
    const int m0   = by * 256;
    const int n0   = bx * 256;

    int rowA[2], rowB[2], ldso[2];
    #pragma unroll
    for (int it = 0; it < 2; ++it) {
        const int o  = (it * 8 + wave) * 1024 + lane * 16;
        const int r  = o >> 7;
        const int cb = (o & 127) ^ ((r & 7) << 4);
        rowA[it] = r * (Ktot * 2) + cb;
        rowB[it] = r * (K * 2) + cb;
        ldso[it] = o;
    }

    const char* Ab0 = (const char*)(At + (size_t)m0 * Ktot);
    const char* Ab1 = Ab0 + (size_t)128 * Ktot * 2;
    const char* Bb0 = (const char*)(Bw + (size_t)n0 * K);
    const char* Bb1 = Bb0 + (size_t)128 * K * 2;
    const size_t Best = (size_t)N * K * 2;
    const int nkm = (1 << log2nk) - 1;
    const int kt0 = s * kts;

#define STAGE_A(BUF, KTG) do { \
    const char* _a0 = Ab0 + (size_t)(KTG) * 128; \
    const char* _a1 = Ab1 + (size_t)(KTG) * 128; \
    char* _l = lds[BUF]; \
    gload16(_a0 + rowA[0], _l + ldso[0]); \
    gload16(_a0 + rowA[1], _l + ldso[1]); \
    gload16(_a1 + rowA[0], _l + 16384 + ldso[0]); \
    gload16(_a1 + rowA[1], _l + 16384 + ldso[1]); \
} while (0)

#define STAGE_B(BUF, KTG) do { \
    const int _kg = (KTG); \
    const size_t _bo = (size_t)(_kg >> log2nk) * Best + (size_t)(_kg & nkm) * 128; \
    char* _l = lds[BUF] + 32768; \
    gload16(Bb0 + _bo + rowB[0], _l + ldso[0]); \
    gload16(Bb0 + _bo + rowB[1], _l + ldso[1]); \
    gload16(Bb1 + _bo + rowB[0], _l + 16384 + ldso[0]); \
    gload16(Bb1 + _bo + rowB[1], _l + 16384 + ldso[1]); \
} while (0)

    f32x4 acc[8][4];
    #pragma unroll
    for (int i = 0; i < 8; ++i)
        #pragma unroll
        for (int j = 0; j < 4; ++j) acc[i][j] = f32x4{0.f, 0.f, 0.f, 0.f};

    bf16x8 af[2][4], bfA[2][2], bfB[2][2];

    STAGE_A(0, kt0);
    STAGE_B(0, kt0);
    STAGE_A(1, kt0 + 1);
    __builtin_amdgcn_sched_barrier(0);
    asm volatile("s_waitcnt vmcnt(4)" ::: "memory");
    __builtin_amdgcn_s_barrier();
    __builtin_amdgcn_sched_barrier(0);

    for (int t = 0; t < kts; ++t) {
        const int BUF = t & 1;
        const char* _abase = lds[BUF] + wm * 16384 + fr * 128;
        const char* _bbase = lds[BUF] + 32768 + (wn >> 1) * 16384 + ((wn & 1) * 64 + fr) * 128;
        const int k0 = (fg * 16) ^ swz;
        const int k1 = (64 + fg * 16) ^ swz;

        if (t + 1 < kts) STAGE_B(BUF ^ 1, kt0 + t + 1);

        #pragma unroll
        for (int i = 0; i < 4; ++i) {
            af[0][i] = *(const bf16x8*)(_abase + i * 2048 + k0);
            af[1][i] = *(const bf16x8*)(_abase + i * 2048 + k1);
        }
        #pragma unroll
        for (int j = 0; j < 2; ++j) {
            bfA[0][j] = *(const bf16x8*)(_bbase + j * 2048 + k0);
            bfA[1][j] = *(const bf16x8*)(_bbase + j * 2048 + k1);
        }
        __builtin_amdgcn_s_setprio(1);
        #pragma unroll
        for (int i = 0; i < 4; ++i)
            #pragma unroll
            for (int j = 0; j < 2; ++j) {
                acc[i][j] = __builtin_amdgcn_mfma_f32_16x16x32_bf16(af[0][i], bfA[0][j], acc[i][j], 0, 0, 0);
                acc[i][j] = __builtin_amdgcn_mfma_f32_16x16x32_bf16(af[1][i], bfA[1][j], acc[i][j], 0, 0, 0);
            }
        __builtin_amdgcn_s_setprio(0);

        #pragma unroll
        for (int j = 0; j < 2; ++j) {
            bfB[0][j] = *(const bf16x8*)(_bbase + (2 + j) * 2048 + k0);
            bfB[1][j] = *(const bf16x8*)(_bbase + (2 + j) * 2048 + k1);
        }
        __builtin_amdgcn_s_setprio(1);
        #pragma unroll
        for (int i = 0; i < 4; ++i)
            #pragma unroll
            for (int j = 0; j < 2; ++j) {
                acc[i][2 + j] = __builtin_amdgcn_mfma_f32_16x16x32_bf16(af[0][i], bfB[0][j], acc[i][2 + j], 0, 0, 0);
                acc[i][2 + j] = __builtin_amdgcn_mfma_f32_16x16x32_bf16(af[1][i], bfB[1][j], acc[i][2 + j], 0, 0, 0);
            }
        __builtin_amdgcn_s_setprio(0);

        #pragma unroll
        for (int i = 0; i < 4; ++i) {
            af[0][i] = *(const bf16x8*)(_abase + (4 + i) * 2048 + k0);
            af[1][i] = *(const bf16x8*)(_abase + (4 + i) * 2048 + k1);
        }
        __builtin_amdgcn_s_setprio(1);
        #pragma unroll
        for (int i = 0; i < 4; ++i)
            #pragma unroll
            for (int j = 0; j < 2; ++j) {
                acc[4 + i][2 + j] = __builtin_amdgcn_mfma_f32_16x16x32_bf16(af[0][i], bfB[0][j], acc[4 + i][2 + j], 0, 0, 0);
                acc[4 + i][2 + j] = __builtin_amdgcn_mfma_f32_16x16x32_bf16(af[1][i], bfB[1][j], acc[4 + i][2 + j], 0, 0, 0);
            }
        __builtin_amdgcn_s_setprio(0);

        __builtin_amdgcn_sched_barrier(0);
        __builtin_amdgcn_s_barrier();
        __builtin_amdgcn_sched_barrier(0);

        if (t + 2 < kts) STAGE_A(BUF, kt0 + t + 2);

        __builtin_amdgcn_s_setprio(1);
        #pragma unroll
        for (int i = 0; i < 4; ++i)
            #pragma unroll
            for (int j = 0; j < 2; ++j) {
                acc[4 + i][j] = __builtin_amdgcn_mfma_f32_16x16x32_bf16(af[0][i], bfA[0][j], acc[4 + i][j], 0, 0, 0);
                acc[4 + i][j] = __builtin_amdgcn_mfma_f32_16x16x32_bf16(af[1][i], bfA[1][j], acc[4 + i][j], 0, 0, 0);
            }
        __builtin_amdgcn_s_setprio(0);

        __builtin_amdgcn_sched_barrier(0);
        if (t + 2 < kts) {
            asm volatile("s_waitcnt vmcnt(4)" ::: "memory");
        } else {
            asm volatile("s_waitcnt vmcnt(0)" ::: "memory");
        }
        __builtin_amdgcn_s_barrier();
        __builtin_amdgcn_sched_barrier(0);
    }

    const size_t pbase = ((size_t)s * 8192 + m0 + wm * 128) * N + (n0 + wn * 64);
    #pragma unroll
    for (int mi = 0; mi < 8; ++mi)
        #pragma unroll
        for (int j = 0; j < 4; ++j) {
            const int r = mi * 16 + fg * 4 + j;
            #pragma unroll
            for (int ni = 0; ni < 4; ++ni) {
                const size_t off = pbase + (size_t)r * N + ni * 16 + fr;
                if (BF16P) ((u16*)P)[off]   = f2bf(acc[mi][ni][j]);
                else       ((float*)P)[off] = acc[mi][ni][j];
            }
        }
#undef STAGE_A
#undef STAGE_B
}

// ---------------- split-K reduce (bf16 partials): + gate-bias -----------------
template<int S>
__global__ void moe_reduce_bf16(const u16* __restrict__ P,
                                const float* __restrict__ gate,
                                const float* __restrict__ bias,
                                float* __restrict__ outp,
                                int log2N) {
    const int i = blockIdx.x * 256 + threadIdx.x;
    const size_t el = (size_t)i * 8;
    const size_t b = el >> log2N;
    const int n = (int)(el & ((1 << log2N) - 1));
    const size_t MN = (size_t)8192 << log2N;
    float v[8];
    u16x8 p0 = *(const u16x8*)(P + el);
    #pragma unroll
    for (int j = 0; j < 8; ++j) v[j] = bf2f(p0[j]);
    #pragma unroll
    for (int s = 1; s < S; ++s) {
        u16x8 ps = *(const u16x8*)(P + (size_t)s * MN + el);
        #pragma unroll
        for (int j = 0; j < 8; ++j) v[j] += bf2f(ps[j]);
    }
    #pragma unroll
    for (int e = 0; e < 8; ++e) {
        const float g = gate[b * 8 + e];
        const float* bb = bias + ((size_t)e << log2N) + n;
        float4 b0 = ((const float4*)bb)[0], b1 = ((const float4*)bb)[1];
        v[0] += g * b0.x; v[1] += g * b0.y; v[2] += g * b0.z; v[3] += g * b0.w;
        v[4] += g * b1.x; v[5] += g * b1.y; v[6] += g * b1.z; v[7] += g * b1.w;
    }
    float4 o0 = {v[0], v[1], v[2], v[3]};
    float4 o1 = {v[4], v[5], v[6], v[7]};
    ((float4*)(outp + el))[0] = o0;
    ((float4*)(outp + el))[1] = o1;
}

// ---- fused: reduce(S=2 bf16, bias b2, ELU) + atilde (8 gated expert copies) --
__global__ void reduce_atilde2(const u16* __restrict__ P,
                               const float* __restrict__ gate,
                               const float* __restrict__ bias,
                               u16* __restrict__ At) {
    const int idx = blockIdx.x * 256 + threadIdx.x;   // 8192*128 total
    const int h = (idx & 127) * 8;
    const size_t b = idx >> 7;
    const size_t MH = (size_t)8192 * 1024;
    const u16* p = P + b * 1024 + h;
    u16x8 a0 = *(const u16x8*)p;
    u16x8 a1 = *(const u16x8*)(p + MH);
    float m[8];
    #pragma unroll
    for (int j = 0; j < 8; ++j) m[j] = bf2f(a0[j]) + bf2f(a1[j]);
    float4 g0 = *(const float4*)&gate[b * 8];
    float4 g1 = *(const float4*)&gate[b * 8 + 4];
    float gg[8] = {g0.x, g0.y, g0.z, g0.w, g1.x, g1.y, g1.z, g1.w};
    #pragma unroll
    for (int e = 0; e < 8; ++e) {
        const float* bb = bias + e * 1024 + h;
        float4 b0 = ((const float4*)bb)[0], b1 = ((const float4*)bb)[1];
        m[0] += gg[e] * b0.x; m[1] += gg[e] * b0.y; m[2] += gg[e] * b0.z; m[3] += gg[e] * b0.w;
        m[4] += gg[e] * b1.x; m[5] += gg[e] * b1.y; m[6] += gg[e] * b1.z; m[7] += gg[e] * b1.w;
    }
    #pragma unroll
    for (int j = 0; j < 8; ++j) m[j] = m[j] > 0.f ? m[j] : expm1f(m[j]);
    u16* o = At + b * 8192 + h;
    #pragma unroll
    for (int e = 0; e < 8; ++e) {
        u16x8 r;
        #pragma unroll
        for (int j = 0; j < 8; ++j) r[j] = f2bf(gg[e] * m[j]);
        *(u16x8*)(o + e * 1024) = r;
    }
}

// ---------------- launcher ----------------------------------------------------
extern "C" void kernel_launch(void* const* d_in, const int* in_sizes, int n_in,
                              void* d_out, int out_size, void* d_ws, size_t ws_size,
                              hipStream_t stream) {
    const float* X  = (const float*)d_in[0];   // [8192,512]
    const float* W  = (const float*)d_in[1];   // [8192,8]
    const float* W1 = (const float*)d_in[2];   // [8,1024,512]
    const float* b1 = (const float*)d_in[3];   // [8,1024]
    const float* W2 = (const float*)d_in[4];   // [8,1024,1024]
    const float* b2 = (const float*)d_in[5];   // [8,1024]
    const float* W3 = (const float*)d_in[6];   // [8,512,1024]
    const float* b3 = (const float*)d_in[7];   // [8,512]
    float* out = (float*)d_out;

    char* ws = (char*)d_ws;
    u16* W1b  = (u16*)ws;  ws += (size_t)8 * 1024 * 512 * 2;     //  8.4 MB
    u16* W2b  = (u16*)ws;  ws += (size_t)8 * 1024 * 1024 * 2;    // 16.8 MB
    u16* W3b  = (u16*)ws;  ws += (size_t)8 * 512 * 1024 * 2;     //  8.4 MB
    u16* At1  = (u16*)ws;  ws += (size_t)8192 * 4096 * 2;        //   67 MB
    u16* At2  = (u16*)ws;  ws += (size_t)8192 * 8192 * 2;        //  134 MB

    // bf16 partial slabs reuse dead regions of At1 (67 MB):
    u16* P2 = At1;   // S=2 x [8192][1024] bf16 = 33.5 MB  (At1 dead after L1)
    u16* P3 = At1;   // S=4 x [8192][512]  bf16 = 33.5 MB  (P2 consumed)

    dim3 blk(256);

    // fused prologue: weight converts + At1 = gate ⊙ X (one dispatch)
    prologue<<<24576, blk, 0, stream>>>(W1, W2, W3, W1b, X, W, At1);

    // L1: fused S=1 GEMM over At1 -> At2 (bias+ELU+8 gated copies)
    moe_gemm_l1f<<<512, blk, 0, stream>>>(At1, W1b, W, b1, At2, 1024, 512, 4096, 3, 64);

    // L2: S=2 GEMM over At2 (bf16 partials); fused reduce+atilde -> At3(=At2)
    moe_gemm_2b<true><<<256, 512, 0, stream>>>(At2, W2b, (void*)P2, 1024, 1024, 8192, 4, 64, 2);
    reduce_atilde2<<<4096, blk, 0, stream>>>(P2, W, b2, At2);

    // L3: S=4 GEMM over At2 (bf16 partials); reduce -> out (f32)
    moe_gemm_2b<true><<<256, 512, 0, stream>>>(At2, W3b, (void*)P3, 512, 1024, 8192, 4, 32, 1);
    moe_reduce_bf16<4><<<2048, blk, 0, stream>>>(P3, W, b3, out, 9);
}